// Round 1
// baseline (313.572 us; speedup 1.0000x reference)
//
#include <hip/hip_runtime.h>

// Problem constants (from reference setup_inputs)
#define B_ 16
#define D_ 64
#define H_ 64
#define W_ 64
#define HW_ 4096          // H*W
#define K_ 1024           // codebook size
#define NPTS_ 65536       // B*H*W
#define QOUT_ 4194304     // B*D*H*W, offset of idx region in d_out

// ---- codebook squared-norm precompute: cnorm[k] = sum_d cb[k][d]^2 ----
__global__ __launch_bounds__(256) void vq_cnorm_kernel(const float* __restrict__ cb,
                                                       float* __restrict__ cnorm) {
    int k = blockIdx.x * 256 + threadIdx.x;
    if (k >= K_) return;
    const float4* c = (const float4*)(cb + (size_t)k * D_);
    float s0 = 0.f, s1 = 0.f, s2 = 0.f, s3 = 0.f;
#pragma unroll
    for (int i = 0; i < D_ / 4; ++i) {
        float4 v = c[i];
        s0 = fmaf(v.x, v.x, s0);
        s1 = fmaf(v.y, v.y, s1);
        s2 = fmaf(v.z, v.z, s2);
        s3 = fmaf(v.w, v.w, s3);
    }
    cnorm[k] = (s0 + s1) + (s2 + s3);
}

// ---- main VQ kernel: one thread per spatial point ----
// x: (B, D, H, W) fp32. Point p = b*HW + hw has features x[b, :, hw] with
// stride HW -> per-d loads are coalesced across lanes (lanes span w).
// Codebook accesses are wave-uniform (same k for all lanes) -> scalar loads
// (s_load_dwordx16) + v_fma with SGPR operand; no LDS needed.
__global__ __launch_bounds__(256) void vq_main_kernel(const float* __restrict__ x,
                                                      const float* __restrict__ cb,
                                                      const float* __restrict__ cnorm,
                                                      float* __restrict__ out) {
    const int p  = blockIdx.x * 256 + threadIdx.x;   // 0..65535
    const int b  = p >> 12;                          // p / 4096
    const int hw = p & 4095;

    const float* xp = x + (size_t)b * (D_ * HW_) + hw;
    float xv[D_];
#pragma unroll
    for (int d = 0; d < D_; ++d) xv[d] = xp[(size_t)d * HW_];

    float best = 3.4e38f;
    int   bidx = 0;
    for (int k = 0; k < K_; ++k) {
        const float* __restrict__ c = cb + (size_t)k * D_;
        float a0 = 0.f, a1 = 0.f, a2 = 0.f, a3 = 0.f;
#pragma unroll
        for (int d = 0; d < D_; d += 4) {
            a0 = fmaf(xv[d + 0], c[d + 0], a0);
            a1 = fmaf(xv[d + 1], c[d + 1], a1);
            a2 = fmaf(xv[d + 2], c[d + 2], a2);
            a3 = fmaf(xv[d + 3], c[d + 3], a3);
        }
        const float dot = (a0 + a1) + (a2 + a3);
        const float d2  = fmaf(-2.f, dot, cnorm[k]);
        if (d2 < best) { best = d2; bidx = k; }   // strict < keeps FIRST min (np.argmin)
    }

    // Gather winning codebook row (per-lane bidx -> vector loads, L2-resident)
    const float4* cw = (const float4*)(cb + (size_t)bidx * D_);
    float4 q[D_ / 4];
#pragma unroll
    for (int i = 0; i < D_ / 4; ++i) q[i] = cw[i];

    // quantized output, (B, D, H, W) layout: coalesced per-d stores
    float* op = out + (size_t)b * (D_ * HW_) + hw;
#pragma unroll
    for (int i = 0; i < D_ / 4; ++i) {
        op[(size_t)(4 * i + 0) * HW_] = q[i].x;
        op[(size_t)(4 * i + 1) * HW_] = q[i].y;
        op[(size_t)(4 * i + 2) * HW_] = q[i].z;
        op[(size_t)(4 * i + 3) * HW_] = q[i].w;
    }
    // index output (stored as float; values <= 1023 are exact)
    out[(size_t)QOUT_ + p] = (float)bidx;
}

extern "C" void kernel_launch(void* const* d_in, const int* in_sizes, int n_in,
                              void* d_out, int out_size, void* d_ws, size_t ws_size,
                              hipStream_t stream) {
    const float* x  = (const float*)d_in[0];   // (16, 64, 64, 64)
    const float* cb = (const float*)d_in[1];   // (1024, 64)
    float* out   = (float*)d_out;              // 4194304 quantized + 65536 idx
    float* cnorm = (float*)d_ws;               // 1024 floats scratch

    vq_cnorm_kernel<<<K_ / 256, 256, 0, stream>>>(cb, cnorm);
    vq_main_kernel<<<NPTS_ / 256, 256, 0, stream>>>(x, cb, cnorm, out);
}

// Round 2
// 124.634 us; speedup vs baseline: 2.5159x; 2.5159x over previous
//
#include <hip/hip_runtime.h>

// Problem constants
#define D_ 64
#define HW_ 4096
#define K_ 1024
#define NPTS_ 65536
#define QOUT_ 4194304     // B*D*H*W, offset of idx region in d_out

// Tiling
#define NW 8              // waves per block
#define CPW 8             // codes per wave per step
#define KSTEP (NW*CPW)    // 64 codes per step
#define NSTEPS (K_/KSTEP) // 16
#define P_ 4              // points per thread (per lane)
#define BLK 512

__device__ __forceinline__ void gload_lds16(const float* g, float* l) {
    __builtin_amdgcn_global_load_lds((const __attribute__((address_space(1))) void*)g,
                                     (__attribute__((address_space(3))) void*)l, 16, 0, 0);
}
__device__ __forceinline__ void gload_lds4(const float* g, float* l) {
    __builtin_amdgcn_global_load_lds((const __attribute__((address_space(1))) void*)g,
                                     (__attribute__((address_space(3))) void*)l, 4, 0, 0);
}

// ---- codebook squared-norm precompute: cnorm[k] = sum_d cb[k][d]^2 ----
__global__ __launch_bounds__(256) void vq_cnorm_kernel(const float* __restrict__ cb,
                                                       float* __restrict__ cnorm) {
    int k = blockIdx.x * 256 + threadIdx.x;
    if (k >= K_) return;
    const float4* c = (const float4*)(cb + (size_t)k * D_);
    float s0 = 0.f, s1 = 0.f, s2 = 0.f, s3 = 0.f;
#pragma unroll
    for (int i = 0; i < D_ / 4; ++i) {
        float4 v = c[i];
        s0 = fmaf(v.x, v.x, s0);
        s1 = fmaf(v.y, v.y, s1);
        s2 = fmaf(v.z, v.z, s2);
        s3 = fmaf(v.w, v.w, s3);
    }
    cnorm[k] = (s0 + s1) + (s2 + s3);
}

// ---- fused GEMM-argmin ----
// Block: 512 thr (8 waves), 256 points. All waves share x tile (LDS); each
// wave owns 8 codes per 64-code step (K-split). acc[4 pts][8 codes] in VGPRs.
__global__ __launch_bounds__(BLK, 2) void vq_main_kernel(const float* __restrict__ x,
                                                         const float* __restrict__ cb,
                                                         const float* __restrict__ cnorm,
                                                         float* __restrict__ out) {
    __shared__ float xt[16 * 256 * 4];        // 64 KB: x tile [dgroup][pt][4]
    __shared__ float cbt[2][KSTEP][D_];       // 32 KB: codebook double-buffer
    __shared__ float cnt[2][KSTEP];           // 512 B: cnorm double-buffer

    const int tid  = threadIdx.x;
    const int lane = tid & 63;
    const int wid  = tid >> 6;
    const int bb   = blockIdx.x >> 4;         // batch index
    const int hw0  = (blockIdx.x & 15) << 8;  // first point (hw) of block

    // ---- stage x tile: global (b, d, hw) -> LDS [dgroup][pt][4] ----
    {
        const int pt = tid & 255;
        const int dh = tid >> 8;              // 0/1: which half of d
        const float* xp = x + (size_t)bb * (D_ * HW_) + hw0 + pt;
        float4* xtv = (float4*)xt;
#pragma unroll
        for (int g = 0; g < 8; ++g) {
            const int dg = dh * 8 + g;
            float4 v;
            v.x = xp[(size_t)(4 * dg + 0) * HW_];
            v.y = xp[(size_t)(4 * dg + 1) * HW_];
            v.z = xp[(size_t)(4 * dg + 2) * HW_];
            v.w = xp[(size_t)(4 * dg + 3) * HW_];
            xtv[dg * 256 + pt] = v;           // contiguous across lanes
        }
    }

    // ---- stage first codebook tile (step 0) ----
    {
        const float* gsrc = cb + (size_t)wid * 512 + lane * 4;
        float* ldst = &cbt[0][0][0] + wid * 512;
        gload_lds16(gsrc, ldst);
        gload_lds16(gsrc + 256, ldst + 256);
        if (wid == 0) gload_lds4(cnorm + lane, &cnt[0][0]);
    }
    asm volatile("s_waitcnt vmcnt(0)" ::: "memory");
    __syncthreads();

    float best[P_];
    int   bid[P_];
#pragma unroll
    for (int p = 0; p < P_; ++p) { best[p] = 3.4e38f; bid[p] = 0; }

    int cur = 0;
#pragma unroll 1
    for (int s = 0; s < NSTEPS; ++s) {
        // prefetch next tile into buf cur^1 (lands under this step's compute)
        if (s + 1 < NSTEPS) {
            const int k0n = (s + 1) * KSTEP;
            const float* gsrc = cb + (size_t)k0n * D_ + wid * 512 + lane * 4;
            float* ldst = &cbt[cur ^ 1][0][0] + wid * 512;
            gload_lds16(gsrc, ldst);
            gload_lds16(gsrc + 256, ldst + 256);
            if (wid == 0) gload_lds4(cnorm + k0n + lane, &cnt[cur ^ 1][0]);
        }

        float acc[P_][CPW] = {};
        const float4* xv = (const float4*)xt;
        const float4* cv = (const float4*)&cbt[cur][0][0];
#pragma unroll
        for (int dg = 0; dg < 16; ++dg) {
            float4 xf[P_];
#pragma unroll
            for (int p = 0; p < P_; ++p) xf[p] = xv[dg * 256 + p * 64 + lane];
            float4 cf[CPW];
#pragma unroll
            for (int c = 0; c < CPW; ++c) cf[c] = cv[(wid * CPW + c) * 16 + dg]; // uniform -> broadcast
#pragma unroll
            for (int p = 0; p < P_; ++p)
#pragma unroll
                for (int c = 0; c < CPW; ++c) {
                    acc[p][c] = fmaf(xf[p].x, cf[c].x, acc[p][c]);
                    acc[p][c] = fmaf(xf[p].y, cf[c].y, acc[p][c]);
                    acc[p][c] = fmaf(xf[p].z, cf[c].z, acc[p][c]);
                    acc[p][c] = fmaf(xf[p].w, cf[c].w, acc[p][c]);
                }
        }

        // fused argmin epilogue for this step's codes (k ascending per thread)
        const int kb = s * KSTEP + wid * CPW;
#pragma unroll
        for (int c = 0; c < CPW; ++c) {
            const float cn = cnt[cur][wid * CPW + c];
#pragma unroll
            for (int p = 0; p < P_; ++p) {
                const float d2 = fmaf(-2.f, acc[p][c], cn);
                if (d2 < best[p]) { best[p] = d2; bid[p] = kb + c; }
            }
        }

        asm volatile("s_waitcnt vmcnt(0)" ::: "memory");
        __syncthreads();
        cur ^= 1;
    }

    // ---- cross-wave argmin reduce (8 candidates per point), alias cbt ----
    float* red_d2 = &cbt[0][0][0];            // 8 KB used
    int*   red_id = (int*)&cbt[1][0][0];      // 8 KB used
#pragma unroll
    for (int p = 0; p < P_; ++p) {
        const int pt = p * 64 + lane;
        red_d2[wid * 256 + pt] = best[p];
        red_id[wid * 256 + pt] = bid[p];
    }
    __syncthreads();

    if (tid < 256) {
        const int pt = tid;
        float b = red_d2[pt];
        int   bi = red_id[pt];
#pragma unroll
        for (int w = 1; w < NW; ++w) {
            const float d2 = red_d2[w * 256 + pt];
            const int   id = red_id[w * 256 + pt];
            if (d2 < b || (d2 == b && id < bi)) { b = d2; bi = id; }  // np.argmin: first min
        }
        // gather winning row + write outputs
        const float4* cw = (const float4*)(cb + (size_t)bi * D_);
        float* op = out + (size_t)bb * (D_ * HW_) + hw0 + pt;
#pragma unroll
        for (int i = 0; i < 16; ++i) {
            const float4 q = cw[i];
            op[(size_t)(4 * i + 0) * HW_] = q.x;
            op[(size_t)(4 * i + 1) * HW_] = q.y;
            op[(size_t)(4 * i + 2) * HW_] = q.z;
            op[(size_t)(4 * i + 3) * HW_] = q.w;
        }
        out[(size_t)QOUT_ + (blockIdx.x << 8) + pt] = (float)bi;
    }
}

extern "C" void kernel_launch(void* const* d_in, const int* in_sizes, int n_in,
                              void* d_out, int out_size, void* d_ws, size_t ws_size,
                              hipStream_t stream) {
    const float* x  = (const float*)d_in[0];   // (16, 64, 64, 64)
    const float* cb = (const float*)d_in[1];   // (1024, 64)
    float* out   = (float*)d_out;
    float* cnorm = (float*)d_ws;               // 1024 floats scratch

    vq_cnorm_kernel<<<K_ / 256, 256, 0, stream>>>(cb, cnorm);
    vq_main_kernel<<<NPTS_ / 256, BLK, 0, stream>>>(x, cb, cnorm, out);
}

// Round 3
// 89.468 us; speedup vs baseline: 3.5049x; 1.3931x over previous
//
#include <hip/hip_runtime.h>
#include <hip/hip_bf16.h>

#define D_ 64
#define HW_ 4096
#define K_ 1024
#define NPTS_ 65536
#define QOUT_ 4194304      // B*D*H*W, offset of idx region in d_out
#define DELTA 0.02f        // ambiguity margin >> 2*eps(bf16-split)
#define INF_ 3.4e38f

typedef short bf16x8 __attribute__((ext_vector_type(8)));
typedef float f32x4 __attribute__((ext_vector_type(4)));

__device__ __forceinline__ void gload_lds16(const float* g, float* l) {
    __builtin_amdgcn_global_load_lds((const __attribute__((address_space(1))) void*)g,
                                     (__attribute__((address_space(3))) void*)l, 16, 0, 0);
}
__device__ __forceinline__ void gload_lds4(const float* g, float* l) {
    __builtin_amdgcn_global_load_lds((const __attribute__((address_space(1))) void*)g,
                                     (__attribute__((address_space(3))) void*)l, 4, 0, 0);
}

// ---- pack kernel: cnorm + bf16 hi/lo split of codebook in MFMA-fragment order ----
// P layout: [chunk c(64)][kstep s(2)][level v(2)][lane l(64)][8 bf16]
//   code j = c*16 + (l&15), dims d = s*32 + (l>>4)*8 + b
__global__ __launch_bounds__(256) void vq_pack(const float* __restrict__ cb,
                                               float* __restrict__ cnorm,
                                               short* __restrict__ P) {
    const int t = blockIdx.x * 256 + threadIdx.x;   // 0..4095
    const int c = t >> 6, l = t & 63;
    const int j  = c * 16 + (l & 15);
    const int dg = l >> 4;
#pragma unroll
    for (int s = 0; s < 2; ++s) {
        const float* src = cb + j * 64 + s * 32 + dg * 8;
        short hb[8], lb[8];
#pragma unroll
        for (int i = 0; i < 8; ++i) {
            const float v = src[i];
            __hip_bfloat16 h = __float2bfloat16(v);
            hb[i] = *(const short*)&h;
            const float r = v - __bfloat162float(h);
            __hip_bfloat16 lo = __float2bfloat16(r);
            lb[i] = *(const short*)&lo;
        }
        short* dh = P + (size_t)((c * 4 + s * 2 + 0) * 64 + l) * 8;
        short* dl = P + (size_t)((c * 4 + s * 2 + 1) * 64 + l) * 8;
#pragma unroll
        for (int i = 0; i < 8; ++i) { dh[i] = hb[i]; dl[i] = lb[i]; }
    }
    if (t < K_) {
        const float4* r = (const float4*)(cb + (size_t)t * 64);
        float s0 = 0.f, s1 = 0.f, s2 = 0.f, s3 = 0.f;
#pragma unroll
        for (int i = 0; i < 16; ++i) {
            float4 v = r[i];
            s0 = fmaf(v.x, v.x, s0); s1 = fmaf(v.y, v.y, s1);
            s2 = fmaf(v.z, v.z, s2); s3 = fmaf(v.w, v.w, s3);
        }
        cnorm[t] = (s0 + s1) + (s2 + s3);
    }
}

// ---- main: MFMA GEMM-argmin with (m1,i1,m2) tracking + exact-fp32 fallback ----
// Block 512 thr (8 waves) x 256 points; wave owns 32 points (2 16-pt tiles),
// scans all 1024 codes in 16-code chunks (2 k-steps of 32 dims each).
__global__ __launch_bounds__(512, 2) void vq_main(const float* __restrict__ x,
                                                  const float* __restrict__ cb,
                                                  const float* __restrict__ cnorm_g,
                                                  const short* __restrict__ P,
                                                  float* __restrict__ out) {
    __shared__ short cbuf[2][8192];   // 2 x 16 KB: 4 chunks x 4 frags x 64 lanes x 8 bf16
    __shared__ float cnt[K_];         // 4 KB
    __shared__ int   res_idx[256];
    __shared__ int   res_flag[256];
    __shared__ int   flist[256];
    __shared__ int   fcnt;

    const int tid  = threadIdx.x;
    const int lane = tid & 63;
    const int wid  = tid >> 6;
    const int bb   = blockIdx.x >> 4;
    const int hw0  = (blockIdx.x & 15) << 8;

    if (tid == 0) fcnt = 0;

    // stage cnorm (1024 f32)
    {
        float* dst = cnt + wid * 64;                       // wave-uniform base
        gload_lds4(cnorm_g + wid * 64 + lane, dst);
        gload_lds4(cnorm_g + 512 + wid * 64 + lane, dst + 512);
    }
    // stage superstep 0 of packed codebook (16 KB)
    {
        const float* Pf = (const float*)P;
        float* dst = (float*)&cbuf[0][0] + wid * 256;      // wave-uniform base
        gload_lds16(Pf + wid * 256 + lane * 4, dst);
        gload_lds16(Pf + 2048 + wid * 256 + lane * 4, dst + 2048);
    }

    // load + split x fragments (persistent): A[t][s], lane holds point (l&15), dims (l>>4)*8..+7
    bf16x8 ah[2][2], al[2][2];
    {
        const float* xb = x + (size_t)bb * (D_ * HW_) + hw0;
#pragma unroll
        for (int t = 0; t < 2; ++t) {
            const int p_l = wid * 32 + t * 16 + (lane & 15);
#pragma unroll
            for (int s = 0; s < 2; ++s) {
                const int d0 = s * 32 + (lane >> 4) * 8;
#pragma unroll
                for (int i = 0; i < 8; ++i) {
                    const float v = xb[(size_t)(d0 + i) * HW_ + p_l];
                    __hip_bfloat16 h = __float2bfloat16(v);
                    ah[t][s][i] = *(const short*)&h;
                    const float r = v - __bfloat162float(h);
                    __hip_bfloat16 lo = __float2bfloat16(r);
                    al[t][s][i] = *(const short*)&lo;
                }
            }
        }
    }
    __syncthreads();

    // running (m1, i1, m2) per slot: slot = t*4 + reg -> point wid*32 + t*16 + 4*(lane>>4) + reg
    float m1[8], m2[8];
    int   i1[8];
#pragma unroll
    for (int q = 0; q < 8; ++q) { m1[q] = INF_; m2[q] = INF_; i1[q] = 0; }

    int cur = 0;
#pragma unroll 1
    for (int ss = 0; ss < 16; ++ss) {
        if (ss + 1 < 16) {   // prefetch next 16 KB superstep
            const float* Pf = (const float*)P + (ss + 1) * 4096;
            float* dst = (float*)&cbuf[cur ^ 1][0] + wid * 256;
            gload_lds16(Pf + wid * 256 + lane * 4, dst);
            gload_lds16(Pf + 2048 + wid * 256 + lane * 4, dst + 2048);
        }
        const bf16x8* fr = (const bf16x8*)&cbuf[cur][0];
#pragma unroll
        for (int ch = 0; ch < 4; ++ch) {
            const int cbase = ss * 64 + ch * 16;
            bf16x8 bh0 = fr[(ch * 4 + 0) * 64 + lane];
            bf16x8 bl0 = fr[(ch * 4 + 1) * 64 + lane];
            bf16x8 bh1 = fr[(ch * 4 + 2) * 64 + lane];
            bf16x8 bl1 = fr[(ch * 4 + 3) * 64 + lane];
            f32x4 acc0 = {0.f, 0.f, 0.f, 0.f};
            f32x4 acc1 = {0.f, 0.f, 0.f, 0.f};
            acc0 = __builtin_amdgcn_mfma_f32_16x16x32_bf16(ah[0][0], bh0, acc0, 0, 0, 0);
            acc0 = __builtin_amdgcn_mfma_f32_16x16x32_bf16(al[0][0], bh0, acc0, 0, 0, 0);
            acc0 = __builtin_amdgcn_mfma_f32_16x16x32_bf16(ah[0][0], bl0, acc0, 0, 0, 0);
            acc0 = __builtin_amdgcn_mfma_f32_16x16x32_bf16(ah[0][1], bh1, acc0, 0, 0, 0);
            acc0 = __builtin_amdgcn_mfma_f32_16x16x32_bf16(al[0][1], bh1, acc0, 0, 0, 0);
            acc0 = __builtin_amdgcn_mfma_f32_16x16x32_bf16(ah[0][1], bl1, acc0, 0, 0, 0);
            acc1 = __builtin_amdgcn_mfma_f32_16x16x32_bf16(ah[1][0], bh0, acc1, 0, 0, 0);
            acc1 = __builtin_amdgcn_mfma_f32_16x16x32_bf16(al[1][0], bh0, acc1, 0, 0, 0);
            acc1 = __builtin_amdgcn_mfma_f32_16x16x32_bf16(ah[1][0], bl0, acc1, 0, 0, 0);
            acc1 = __builtin_amdgcn_mfma_f32_16x16x32_bf16(ah[1][1], bh1, acc1, 0, 0, 0);
            acc1 = __builtin_amdgcn_mfma_f32_16x16x32_bf16(al[1][1], bh1, acc1, 0, 0, 0);
            acc1 = __builtin_amdgcn_mfma_f32_16x16x32_bf16(ah[1][1], bl1, acc1, 0, 0, 0);

            const int   kc = cbase + (lane & 15);
            const float cn = cnt[kc];
#pragma unroll
            for (int t = 0; t < 2; ++t)
#pragma unroll
                for (int r = 0; r < 4; ++r) {
                    const int q = t * 4 + r;
                    const float d2 = fmaf(-2.f, (t == 0) ? acc0[r] : acc1[r], cn);
                    if (d2 < m1[q]) { m2[q] = m1[q]; m1[q] = d2; i1[q] = kc; }
                    else            { m2[q] = fminf(m2[q], d2); }
                }
        }
        __syncthreads();   // drains vmcnt (prefetch) + lgkm before buffer swap
        cur ^= 1;
    }

    // cross-lane (m1,i1,m2) reduce over the 16 lanes sharing (lane>>4)
#pragma unroll
    for (int q = 0; q < 8; ++q) {
        float a1 = m1[q], a2 = m2[q];
        int   ai = i1[q];
#pragma unroll
        for (int m = 1; m < 16; m <<= 1) {
            const float o1 = __shfl_xor(a1, m);
            const int   oi = __shfl_xor(ai, m);
            const float o2 = __shfl_xor(a2, m);
            const float nm2 = fminf(fminf(a2, o2), fmaxf(a1, o1));
            if (o1 < a1 || (o1 == a1 && oi < ai)) { a1 = o1; ai = oi; }
            a2 = nm2;
        }
        if ((lane & 15) == 0) {
            const int t = q >> 2, r = q & 3;
            const int pt = wid * 32 + t * 16 + 4 * (lane >> 4) + r;
            res_idx[pt]  = ai;
            res_flag[pt] = (a2 - a1 <= DELTA) ? 1 : 0;
        }
    }
    __syncthreads();

    // fallback list
    if (tid < 256 && res_flag[tid]) { const int p = atomicAdd(&fcnt, 1); flist[p] = tid; }
    __syncthreads();

    // exact fp32 rescan for ambiguous points (wave-cooperative, 16 codes/lane)
    const int nf = fcnt;
    for (int i = wid; i < nf; i += 8) {
        const int pt = flist[i];
        const float* xr = x + (size_t)bb * (D_ * HW_) + hw0 + pt;
        float acc[16];
#pragma unroll
        for (int c = 0; c < 16; ++c) acc[c] = 0.f;
        for (int d = 0; d < 64; d += 4) {
            const float x0 = xr[(size_t)(d + 0) * HW_];
            const float x1 = xr[(size_t)(d + 1) * HW_];
            const float x2 = xr[(size_t)(d + 2) * HW_];
            const float x3 = xr[(size_t)(d + 3) * HW_];
#pragma unroll
            for (int c = 0; c < 16; ++c) {
                const float4 cf = *(const float4*)(cb + (size_t)(lane * 16 + c) * 64 + d);
                acc[c] = fmaf(x0, cf.x, fmaf(x1, cf.y, fmaf(x2, cf.z, fmaf(x3, cf.w, acc[c]))));
            }
        }
        float b1 = INF_; int bi = 0;
#pragma unroll
        for (int c = 0; c < 16; ++c) {
            const float d2 = fmaf(-2.f, acc[c], cnt[lane * 16 + c]);
            if (d2 < b1) { b1 = d2; bi = lane * 16 + c; }
        }
#pragma unroll
        for (int m = 1; m < 64; m <<= 1) {
            const float o1 = __shfl_xor(b1, m);
            const int   oi = __shfl_xor(bi, m);
            if (o1 < b1 || (o1 == b1 && oi < bi)) { b1 = o1; bi = oi; }
        }
        if (lane == 0) res_idx[pt] = bi;
    }
    __syncthreads();

    // store phase: coalesced across pt
    if (tid < 256) {
        const int pt = tid;
        const int bi = res_idx[pt];
        const float4* cw = (const float4*)(cb + (size_t)bi * 64);
        float* op = out + (size_t)bb * (D_ * HW_) + hw0 + pt;
#pragma unroll
        for (int i = 0; i < 16; ++i) {
            const float4 qv = cw[i];
            op[(size_t)(4 * i + 0) * HW_] = qv.x;
            op[(size_t)(4 * i + 1) * HW_] = qv.y;
            op[(size_t)(4 * i + 2) * HW_] = qv.z;
            op[(size_t)(4 * i + 3) * HW_] = qv.w;
        }
        out[(size_t)QOUT_ + (blockIdx.x << 8) + pt] = (float)bi;
    }
}

extern "C" void kernel_launch(void* const* d_in, const int* in_sizes, int n_in,
                              void* d_out, int out_size, void* d_ws, size_t ws_size,
                              hipStream_t stream) {
    const float* x  = (const float*)d_in[0];   // (16, 64, 64, 64)
    const float* cb = (const float*)d_in[1];   // (1024, 64)
    float* out   = (float*)d_out;
    float* cnorm = (float*)d_ws;                       // 4 KB
    short* P     = (short*)((char*)d_ws + 4096);       // 256 KB packed bf16 codebook

    vq_pack<<<16, 256, 0, stream>>>(cb, cnorm, P);
    vq_main<<<NPTS_ / 256, 512, 0, stream>>>(x, cb, cnorm, P, out);
}